// Round 9
// baseline (536.044 us; speedup 1.0000x reference)
//
#include <hip/hip_runtime.h>
#include <hip/hip_bf16.h>

// B=32, C=128, L=256, K=2. deg==1 -> L_t = -adj.
// out[b] = relu( [x[b] | y[b]] @ [Th0; Th1] ),  y[b][j] = -sum_i adj[i][j] x[i]
// K1 k_pre : pairdist (32x32 i<=j reg-blocked; diagonal tiles also emit xb/xbT)
//            + ssum atomics + thT2 + aT
// K2 k_fuse: per (b, jt16, nhalf): adjacency(from ssum) -> y (MFMA) -> out (MFMA K=512) + ReLU

#define NB 32
#define NC 128
#define NL 256

typedef short bf16x8 __attribute__((ext_vector_type(8)));
typedef float f32x4 __attribute__((ext_vector_type(4)));

static __device__ __forceinline__ unsigned short f2bf(float f) {
    unsigned u = __builtin_bit_cast(unsigned, f);
    u += 0x7fff + ((u >> 16) & 1);            // RNE
    return (unsigned short)(u >> 16);
}

__device__ const unsigned char TI10[10] = {0,0,0,0, 1,1,1, 2,2, 3};
__device__ const unsigned char TJ10[10] = {0,1,2,3, 1,2,3, 2,3, 3};

// ---------------- K1 ----------------
// blocks [0,320): pairdist 32x32 (+cvt on diagonal tiles); [320,352): thT2; [352,356): aT
__global__ __launch_bounds__(256) void k_pre(const float* __restrict__ x,
                                             const float* __restrict__ Theta,
                                             const float* __restrict__ a,
                                             float* __restrict__ diff,
                                             float* __restrict__ ssum,
                                             unsigned short* __restrict__ xb,
                                             unsigned short* __restrict__ xbT,
                                             unsigned short* __restrict__ thT2,
                                             float* __restrict__ aT) {
    __shared__ float smem[4480];   // pairdist: xi[32][68] | xj[32][68] (sT aliases xi); transpose [64][65]
    int bid = blockIdx.x;
    int tid = threadIdx.x;

    if (bid < 320) {
        int b = bid / 10, p = bid - b * 10;
        int i0 = TI10[p] * 32, j0 = TJ10[p] * 32;
        bool diag = (i0 == j0);
        float* xi = smem;              // [32][68]
        float* xj = smem + 2176;       // [32][68]
        const float4* x4 = (const float4*)(x + (size_t)b * NC * NL);
        int il = tid >> 4, jl = tid & 15;
        float a00 = 0.f, a01 = 0.f, a10 = 0.f, a11 = 0.f;
        #pragma unroll
        for (int q = 0; q < 4; ++q) {         // L quarters of 64 floats (16 float4)
            __syncthreads();
            #pragma unroll
            for (int k = 0; k < 2; ++k) {
                int idx = tid + k * 256;      // 512 float4 per buffer
                int r = idx >> 4, c4 = idx & 15;
                *(float4*)&xi[r * 68 + c4 * 4] = x4[(i0 + r) * 64 + q * 16 + c4];
                *(float4*)&xj[r * 68 + c4 * 4] = x4[(j0 + r) * 64 + q * 16 + c4];
            }
            __syncthreads();
            #pragma unroll
            for (int l4 = 0; l4 < 16; ++l4) {
                float4 u0 = *(const float4*)&xi[il * 68 + l4 * 4];
                float4 u1 = *(const float4*)&xi[(il + 16) * 68 + l4 * 4];
                float4 v0 = *(const float4*)&xj[jl * 68 + l4 * 4];
                float4 v1 = *(const float4*)&xj[(jl + 16) * 68 + l4 * 4];
                a00 += fabsf(u0.x-v0.x)+fabsf(u0.y-v0.y)+fabsf(u0.z-v0.z)+fabsf(u0.w-v0.w);
                a01 += fabsf(u0.x-v1.x)+fabsf(u0.y-v1.y)+fabsf(u0.z-v1.z)+fabsf(u0.w-v1.w);
                a10 += fabsf(u1.x-v0.x)+fabsf(u1.y-v0.y)+fabsf(u1.z-v0.z)+fabsf(u1.w-v0.w);
                a11 += fabsf(u1.x-v1.x)+fabsf(u1.y-v1.y)+fabsf(u1.z-v1.z)+fabsf(u1.w-v1.w);
            }
            if (diag) {
                // emit xb / xbT for rows i0..i0+31, cols q*64..q*64+63 from xi (read-only reuse)
                #pragma unroll
                for (int k = 0; k < 2; ++k) {
                    int idx = tid + k * 256;          // 512 ushort4 jobs: xb
                    int r = idx >> 4, c4 = idx & 15;
                    ushort4 o;
                    o.x = f2bf(xi[r * 68 + c4 * 4 + 0]);
                    o.y = f2bf(xi[r * 68 + c4 * 4 + 1]);
                    o.z = f2bf(xi[r * 68 + c4 * 4 + 2]);
                    o.w = f2bf(xi[r * 68 + c4 * 4 + 3]);
                    *(ushort4*)(xb + (size_t)b * 32768 + (size_t)(i0 + r) * 256 + q * 64 + c4 * 4) = o;
                }
                #pragma unroll
                for (int k = 0; k < 2; ++k) {
                    int idx = tid + k * 256;          // 512 ushort4 jobs: xbT
                    int lr_ = idx >> 3, ci = idx & 7; // l-local 0..63, i-chunk 0..7
                    ushort4 p2;
                    p2.x = f2bf(xi[(ci * 4 + 0) * 68 + lr_]);
                    p2.y = f2bf(xi[(ci * 4 + 1) * 68 + lr_]);
                    p2.z = f2bf(xi[(ci * 4 + 2) * 68 + lr_]);
                    p2.w = f2bf(xi[(ci * 4 + 3) * 68 + lr_]);
                    *(ushort4*)(xbT + (size_t)b * 32768 + (size_t)(q * 64 + lr_) * 128 + i0 + ci * 4) = p2;
                }
            }
        }
        float* D = diff + (size_t)b * NC * NC;
        D[(i0 + il) * NC + j0 + jl]           = a00;
        D[(i0 + il) * NC + j0 + jl + 16]      = a01;
        D[(i0 + il + 16) * NC + j0 + jl]      = a10;
        D[(i0 + il + 16) * NC + j0 + jl + 16] = a11;
        atomicAdd(&ssum[(i0 + il) * NC + j0 + jl],           a00 * a00);
        atomicAdd(&ssum[(i0 + il) * NC + j0 + jl + 16],      a01 * a01);
        atomicAdd(&ssum[(i0 + il + 16) * NC + j0 + jl],      a10 * a10);
        atomicAdd(&ssum[(i0 + il + 16) * NC + j0 + jl + 16], a11 * a11);
        if (!diag) {
            atomicAdd(&ssum[(j0 + jl) * NC + i0 + il],           a00 * a00);
            atomicAdd(&ssum[(j0 + jl + 16) * NC + i0 + il],      a01 * a01);
            atomicAdd(&ssum[(j0 + jl) * NC + i0 + il + 16],      a10 * a10);
            atomicAdd(&ssum[(j0 + jl + 16) * NC + i0 + il + 16], a11 * a11);
            float* sT = smem;          // [32][33], aliases xi (done reading)
            __syncthreads();
            sT[jl * 33 + il]             = a00;
            sT[(jl + 16) * 33 + il]      = a01;
            sT[jl * 33 + il + 16]        = a10;
            sT[(jl + 16) * 33 + il + 16] = a11;
            __syncthreads();
            #pragma unroll
            for (int k = 0; k < 4; ++k) {
                int idx = tid + k * 256;
                int r = idx >> 5, c = idx & 31;
                D[(j0 + r) * NC + i0 + c] = sT[r * 33 + c];
            }
        }
    } else if (bid < 352) {
        // thT2[n][t*256 + l] = Theta[t][l][n]
        int tt = bid - 320;
        int t = tt >> 4, rem = tt & 15;
        int l0 = (rem >> 2) * 64, n0 = (rem & 3) * 64;
        const float4* T4 = (const float4*)(Theta + (size_t)t * 65536);
        for (int idx = tid; idx < 1024; idx += 256) {
            int r = idx >> 4, c4 = idx & 15;
            *(float4*)&smem[r * 65 + c4 * 4] = T4[(l0 + r) * 64 + (n0 >> 2) + c4];
        }
        __syncthreads();
        for (int idx = tid; idx < 1024; idx += 256) {
            int r = idx >> 4, c4 = idx & 15;   // row n0+r, l-offset l0+4*c4
            ushort4 o;
            o.x = f2bf(smem[(c4 * 4 + 0) * 65 + r]);
            o.y = f2bf(smem[(c4 * 4 + 1) * 65 + r]);
            o.z = f2bf(smem[(c4 * 4 + 2) * 65 + r]);
            o.w = f2bf(smem[(c4 * 4 + 3) * 65 + r]);
            *(ushort4*)(thT2 + (size_t)(n0 + r) * 512 + t * 256 + l0 + c4 * 4) = o;
        }
    } else {
        // aT[j][i] = a[i][j]
        int tt = bid - 352;
        int i0 = (tt >> 1) * 64, j0 = (tt & 1) * 64;
        for (int it = tid; it < 4096; it += 256) {
            int r = it >> 6, c = it & 63;
            smem[r * 65 + c] = a[(i0 + r) * NC + j0 + c];
        }
        __syncthreads();
        for (int it = tid; it < 4096; it += 256) {
            int r = it >> 6, c = it & 63;
            aT[(j0 + r) * NC + i0 + c] = smem[c * 65 + r];
        }
    }
}

// ---------------- K2: adjacency + y-GEMM + out-GEMM, fused ----------------
// 512 blocks: b*16 + jt*2 + nh. 256 thr (4 waves).
__global__ __launch_bounds__(256) void k_fuse(const float* __restrict__ diff,
                                              const float* __restrict__ ssum,
                                              const float* __restrict__ aT,
                                              const unsigned short* __restrict__ xb,
                                              const unsigned short* __restrict__ xbT,
                                              const unsigned short* __restrict__ thT2,
                                              float* __restrict__ out) {
    __shared__ __align__(16) short adjL[16 * 144];   // [j][i], row stride 288 B, negated adj^T
    __shared__ __align__(16) short yL[16 * 272];     // [j][l], row stride 544 B
    int bid = blockIdx.x;
    int b = bid >> 4, jt = (bid >> 1) & 7, nh = bid & 1;
    int j0 = jt * 16;
    int tid = threadIdx.x;

    // ---- Phase 0: adjacency for 16 j-columns ----
    {
        int jl = tid >> 4, ig = tid & 15;             // j = j0+jl, i = ig + 16*r
        const float* Dp = diff + (size_t)b * NC * NC + (size_t)(j0 + jl) * NC + ig;
        const float* Sp = ssum + (size_t)(j0 + jl) * NC + ig;    // symmetric
        const float* Ap = aT   + (size_t)(j0 + jl) * NC + ig;    // a[i][j]
        float sv[8];
        float cs = 0.f;
        #pragma unroll
        for (int r = 0; r < 8; ++r) {
            int off = 16 * r;
            float rn = 1.0f / fmaxf(sqrtf(Sp[off]), 1e-12f);
            float s = __expf(fmaxf((1.0f - Dp[off] * rn) * Ap[off], 0.0f));
            sv[r] = s;
            cs += s;
        }
        cs += __shfl_xor(cs, 1); cs += __shfl_xor(cs, 2);
        cs += __shfl_xor(cs, 4); cs += __shfl_xor(cs, 8);
        float inv = -1.0f / cs;                       // fold y's negation
        #pragma unroll
        for (int r = 0; r < 8; ++r)
            adjL[jl * 144 + ig + 16 * r] = (short)f2bf(sv[r] * inv);
    }
    __syncthreads();

    int w = tid >> 6, lane = tid & 63, lr = lane & 15, lg = lane >> 4;

    // ---- Phase A: yL[16][256] = adjL @ x[b]  (M=16 j, N=256 l, K=128 i) ----
    {
        f32x4 acc[4];
        #pragma unroll
        for (int f = 0; f < 4; ++f) acc[f] = (f32x4){0.f, 0.f, 0.f, 0.f};
        const unsigned short* Bb = xbT + (size_t)b * 32768;
        #pragma unroll
        for (int ks = 0; ks < 4; ++ks) {
            bf16x8 af = *(const bf16x8*)&adjL[lr * 144 + ks * 32 + lg * 8];
            #pragma unroll
            for (int f = 0; f < 4; ++f) {
                bf16x8 bv = *(const bf16x8*)(Bb + (size_t)(w * 64 + f * 16 + lr) * 128 + ks * 32 + lg * 8);
                acc[f] = __builtin_amdgcn_mfma_f32_16x16x32_bf16(af, bv, acc[f], 0, 0, 0);
            }
        }
        #pragma unroll
        for (int f = 0; f < 4; ++f)
            #pragma unroll
            for (int r = 0; r < 4; ++r)
                yL[(lg * 4 + r) * 272 + w * 64 + f * 16 + lr] = (short)f2bf(acc[f][r]);
    }
    __syncthreads();

    // ---- Phase B: out half (M=16 j, N=128, K=512) ----
    {
        f32x4 o[2];
        o[0] = (f32x4){0.f, 0.f, 0.f, 0.f};
        o[1] = (f32x4){0.f, 0.f, 0.f, 0.f};
        const unsigned short* Arow = xb + (size_t)b * 32768 + (size_t)(j0 + lr) * 256;
        #pragma unroll
        for (int ks = 0; ks < 16; ++ks) {
            bf16x8 af = (ks < 8)
                ? *(const bf16x8*)(Arow + ks * 32 + lg * 8)
                : *(const bf16x8*)&yL[lr * 272 + (ks - 8) * 32 + lg * 8];
            #pragma unroll
            for (int f = 0; f < 2; ++f) {
                int n = nh * 128 + w * 32 + f * 16 + lr;
                bf16x8 bv = *(const bf16x8*)(thT2 + (size_t)n * 512 + ks * 32 + lg * 8);
                o[f] = __builtin_amdgcn_mfma_f32_16x16x32_bf16(af, bv, o[f], 0, 0, 0);
            }
        }
        float* Ob = out + (size_t)b * 32768;
        #pragma unroll
        for (int f = 0; f < 2; ++f)
            #pragma unroll
            for (int r = 0; r < 4; ++r)
                Ob[(size_t)(j0 + lg * 4 + r) * 256 + nh * 128 + w * 32 + f * 16 + lr] =
                    fmaxf(o[f][r], 0.f);
    }
}

extern "C" void kernel_launch(void* const* d_in, const int* in_sizes, int n_in,
                              void* d_out, int out_size, void* d_ws, size_t ws_size,
                              hipStream_t stream) {
    const float* x     = (const float*)d_in[0];   // [32,128,256]
    const float* a     = (const float*)d_in[1];   // [128,128]
    const float* Theta = (const float*)d_in[2];   // [2,256,256]
    float* out = (float*)d_out;
    float* f0  = (float*)d_ws;

    float*          diff  = f0;                                // 524288 f32 (2 MB)
    float*          ssum  = f0 + 524288;                       // 16384 f32
    float*          aT    = f0 + 540672;                       // 16384 f32
    unsigned short* xb    = (unsigned short*)(f0 + 557056);    // 1048576 bf16
    unsigned short* xbT   = (unsigned short*)(f0 + 1081344);   // 1048576 bf16
    unsigned short* thT2  = (unsigned short*)(f0 + 1605632);   // 131072 bf16
    // total 1671168 f32 = 6.68 MB

    hipMemsetAsync(ssum, 0, 16384 * sizeof(float), stream);
    k_pre <<<dim3(356), dim3(256), 0, stream>>>(x, Theta, a, diff, ssum, xb, xbT, thT2, aT);
    k_fuse<<<dim3(512), dim3(256), 0, stream>>>(diff, ssum, aT, xb, xbT, thT2, out);
}

// Round 11
// 90.846 us; speedup vs baseline: 5.9006x; 5.9006x over previous
//
#include <hip/hip_runtime.h>
#include <hip/hip_bf16.h>

// B=32, C=128, L=256, K=2. deg==1 -> L_t = -adj.
// out[b] = relu( [x[b] | y[b]] @ [Th0; Th1] ),  y[b][j] = -sum_i adj[i][j] x[i]
// K1 k_pre : pairdist (32x32 i<=j reg-blocked) + ssum atomics + {xb,xbT} + thT2 + aT
// K2 k_fuse: per (b, jt16, nhalf): adjacency(from ssum) -> y (MFMA) -> out (MFMA K=512) + ReLU
// (= proven R8 structure; R9's diag-cvt fusion spilled to scratch, 5x regression.)

#define NB 32
#define NC 128
#define NL 256

typedef short bf16x8 __attribute__((ext_vector_type(8)));
typedef float f32x4 __attribute__((ext_vector_type(4)));

static __device__ __forceinline__ unsigned short f2bf(float f) {
    unsigned u = __builtin_bit_cast(unsigned, f);
    u += 0x7fff + ((u >> 16) & 1);            // RNE
    return (unsigned short)(u >> 16);
}

__device__ const unsigned char TI10[10] = {0,0,0,0, 1,1,1, 2,2, 3};
__device__ const unsigned char TJ10[10] = {0,1,2,3, 1,2,3, 2,3, 3};

// ---------------- K1 ----------------
// blocks [0,320): pairdist 32x32; [320,576): x->xb+xbT; [576,608): thT2; [608,612): aT
__global__ __launch_bounds__(256) void k_pre(const float* __restrict__ x,
                                             const float* __restrict__ Theta,
                                             const float* __restrict__ a,
                                             float* __restrict__ diff,
                                             float* __restrict__ ssum,
                                             unsigned short* __restrict__ xb,
                                             unsigned short* __restrict__ xbT,
                                             unsigned short* __restrict__ thT2,
                                             float* __restrict__ aT) {
    __shared__ float smem[4480];   // pairdist: xi[32][68] | xj[32][68] (sT aliases xi); transpose [64][65]
    int bid = blockIdx.x;
    int tid = threadIdx.x;

    if (bid < 320) {
        int b = bid / 10, p = bid - b * 10;
        int i0 = TI10[p] * 32, j0 = TJ10[p] * 32;
        float* xi = smem;              // [32][68]
        float* xj = smem + 2176;       // [32][68]
        const float4* x4 = (const float4*)(x + (size_t)b * NC * NL);
        int il = tid >> 4, jl = tid & 15;
        float a00 = 0.f, a01 = 0.f, a10 = 0.f, a11 = 0.f;
        #pragma unroll
        for (int q = 0; q < 4; ++q) {         // L quarters of 64 floats (16 float4)
            __syncthreads();
            #pragma unroll
            for (int k = 0; k < 2; ++k) {
                int idx = tid + k * 256;      // 512 float4 per buffer
                int r = idx >> 4, c4 = idx & 15;
                *(float4*)&xi[r * 68 + c4 * 4] = x4[(i0 + r) * 64 + q * 16 + c4];
                *(float4*)&xj[r * 68 + c4 * 4] = x4[(j0 + r) * 64 + q * 16 + c4];
            }
            __syncthreads();
            #pragma unroll
            for (int l4 = 0; l4 < 16; ++l4) {
                float4 u0 = *(const float4*)&xi[il * 68 + l4 * 4];
                float4 u1 = *(const float4*)&xi[(il + 16) * 68 + l4 * 4];
                float4 v0 = *(const float4*)&xj[jl * 68 + l4 * 4];
                float4 v1 = *(const float4*)&xj[(jl + 16) * 68 + l4 * 4];
                a00 += fabsf(u0.x-v0.x)+fabsf(u0.y-v0.y)+fabsf(u0.z-v0.z)+fabsf(u0.w-v0.w);
                a01 += fabsf(u0.x-v1.x)+fabsf(u0.y-v1.y)+fabsf(u0.z-v1.z)+fabsf(u0.w-v1.w);
                a10 += fabsf(u1.x-v0.x)+fabsf(u1.y-v0.y)+fabsf(u1.z-v0.z)+fabsf(u1.w-v0.w);
                a11 += fabsf(u1.x-v1.x)+fabsf(u1.y-v1.y)+fabsf(u1.z-v1.z)+fabsf(u1.w-v1.w);
            }
        }
        float* D = diff + (size_t)b * NC * NC;
        D[(i0 + il) * NC + j0 + jl]           = a00;
        D[(i0 + il) * NC + j0 + jl + 16]      = a01;
        D[(i0 + il + 16) * NC + j0 + jl]      = a10;
        D[(i0 + il + 16) * NC + j0 + jl + 16] = a11;
        atomicAdd(&ssum[(i0 + il) * NC + j0 + jl],           a00 * a00);
        atomicAdd(&ssum[(i0 + il) * NC + j0 + jl + 16],      a01 * a01);
        atomicAdd(&ssum[(i0 + il + 16) * NC + j0 + jl],      a10 * a10);
        atomicAdd(&ssum[(i0 + il + 16) * NC + j0 + jl + 16], a11 * a11);
        if (i0 != j0) {
            atomicAdd(&ssum[(j0 + jl) * NC + i0 + il],           a00 * a00);
            atomicAdd(&ssum[(j0 + jl + 16) * NC + i0 + il],      a01 * a01);
            atomicAdd(&ssum[(j0 + jl) * NC + i0 + il + 16],      a10 * a10);
            atomicAdd(&ssum[(j0 + jl + 16) * NC + i0 + il + 16], a11 * a11);
            float* sT = smem;          // [32][33], aliases xi (done reading)
            __syncthreads();
            sT[jl * 33 + il]             = a00;
            sT[(jl + 16) * 33 + il]      = a01;
            sT[jl * 33 + il + 16]        = a10;
            sT[(jl + 16) * 33 + il + 16] = a11;
            __syncthreads();
            #pragma unroll
            for (int k = 0; k < 4; ++k) {
                int idx = tid + k * 256;
                int r = idx >> 5, c = idx & 31;
                D[(j0 + r) * NC + i0 + c] = sT[r * 33 + c];
            }
        }
    } else if (bid < 576) {
        // x[b] 64x64 f32 tile -> xb (row-major bf16) + xbT ([l][i] bf16)
        int tt = bid - 320;                      // (b:5, itile:1, ltile:2)
        int b = tt >> 3, rem = tt & 7;
        int i0 = (rem >> 2) * 64, l0 = (rem & 3) * 64;
        const float4* x4 = (const float4*)(x + (size_t)b * NC * NL);
        for (int idx = tid; idx < 1024; idx += 256) {
            int r = idx >> 4, c4 = idx & 15;
            *(float4*)&smem[r * 65 + c4 * 4] = x4[(i0 + r) * 64 + (l0 >> 2) + c4];
        }
        __syncthreads();
        for (int idx = tid; idx < 1024; idx += 256) {
            int r = idx >> 4, c4 = idx & 15;
            ushort4 o;   // xb[i0+r][l0 + 4*c4 ..]
            o.x = f2bf(smem[r * 65 + c4 * 4 + 0]);
            o.y = f2bf(smem[r * 65 + c4 * 4 + 1]);
            o.z = f2bf(smem[r * 65 + c4 * 4 + 2]);
            o.w = f2bf(smem[r * 65 + c4 * 4 + 3]);
            *(ushort4*)(xb + (size_t)b * 32768 + (size_t)(i0 + r) * 256 + l0 + c4 * 4) = o;
            ushort4 p;   // xbT[l0+r][i0 + 4*c4 ..]
            p.x = f2bf(smem[(c4 * 4 + 0) * 65 + r]);
            p.y = f2bf(smem[(c4 * 4 + 1) * 65 + r]);
            p.z = f2bf(smem[(c4 * 4 + 2) * 65 + r]);
            p.w = f2bf(smem[(c4 * 4 + 3) * 65 + r]);
            *(ushort4*)(xbT + (size_t)b * 32768 + (size_t)(l0 + r) * 128 + i0 + c4 * 4) = p;
        }
    } else if (bid < 608) {
        // thT2[n][t*256 + l] = Theta[t][l][n]
        int tt = bid - 576;
        int t = tt >> 4, rem = tt & 15;
        int l0 = (rem >> 2) * 64, n0 = (rem & 3) * 64;
        const float4* T4 = (const float4*)(Theta + (size_t)t * 65536);
        for (int idx = tid; idx < 1024; idx += 256) {
            int r = idx >> 4, c4 = idx & 15;
            *(float4*)&smem[r * 65 + c4 * 4] = T4[(l0 + r) * 64 + (n0 >> 2) + c4];
        }
        __syncthreads();
        for (int idx = tid; idx < 1024; idx += 256) {
            int r = idx >> 4, c4 = idx & 15;   // row n0+r, l-offset l0+4*c4
            ushort4 o;
            o.x = f2bf(smem[(c4 * 4 + 0) * 65 + r]);
            o.y = f2bf(smem[(c4 * 4 + 1) * 65 + r]);
            o.z = f2bf(smem[(c4 * 4 + 2) * 65 + r]);
            o.w = f2bf(smem[(c4 * 4 + 3) * 65 + r]);
            *(ushort4*)(thT2 + (size_t)(n0 + r) * 512 + t * 256 + l0 + c4 * 4) = o;
        }
    } else {
        // aT[j][i] = a[i][j]
        int tt = bid - 608;
        int i0 = (tt >> 1) * 64, j0 = (tt & 1) * 64;
        for (int it = tid; it < 4096; it += 256) {
            int r = it >> 6, c = it & 63;
            smem[r * 65 + c] = a[(i0 + r) * NC + j0 + c];
        }
        __syncthreads();
        for (int it = tid; it < 4096; it += 256) {
            int r = it >> 6, c = it & 63;
            aT[(j0 + r) * NC + i0 + c] = smem[c * 65 + r];
        }
    }
}

// ---------------- K2: adjacency + y-GEMM + out-GEMM, fused ----------------
// 512 blocks: b*16 + jt*2 + nh. 256 thr (4 waves).
__global__ __launch_bounds__(256) void k_fuse(const float* __restrict__ diff,
                                              const float* __restrict__ ssum,
                                              const float* __restrict__ aT,
                                              const unsigned short* __restrict__ xb,
                                              const unsigned short* __restrict__ xbT,
                                              const unsigned short* __restrict__ thT2,
                                              float* __restrict__ out) {
    __shared__ __align__(16) short adjL[16 * 144];   // [j][i], row stride 288 B, negated adj^T
    __shared__ __align__(16) short yL[16 * 272];     // [j][l], row stride 544 B
    int bid = blockIdx.x;
    int b = bid >> 4, jt = (bid >> 1) & 7, nh = bid & 1;
    int j0 = jt * 16;
    int tid = threadIdx.x;

    // ---- Phase 0: adjacency for 16 j-columns ----
    {
        int jl = tid >> 4, ig = tid & 15;             // j = j0+jl, i = ig + 16*r
        const float* Dp = diff + (size_t)b * NC * NC + (size_t)(j0 + jl) * NC + ig;
        const float* Sp = ssum + (size_t)(j0 + jl) * NC + ig;    // symmetric
        const float* Ap = aT   + (size_t)(j0 + jl) * NC + ig;    // a[i][j]
        float sv[8];
        float cs = 0.f;
        #pragma unroll
        for (int r = 0; r < 8; ++r) {
            int off = 16 * r;
            float rn = 1.0f / fmaxf(sqrtf(Sp[off]), 1e-12f);
            float s = __expf(fmaxf((1.0f - Dp[off] * rn) * Ap[off], 0.0f));
            sv[r] = s;
            cs += s;
        }
        cs += __shfl_xor(cs, 1); cs += __shfl_xor(cs, 2);
        cs += __shfl_xor(cs, 4); cs += __shfl_xor(cs, 8);
        float inv = -1.0f / cs;                       // fold y's negation
        #pragma unroll
        for (int r = 0; r < 8; ++r)
            adjL[jl * 144 + ig + 16 * r] = (short)f2bf(sv[r] * inv);
    }
    __syncthreads();

    int w = tid >> 6, lane = tid & 63, lr = lane & 15, lg = lane >> 4;

    // ---- Phase A: yL[16][256] = adjL @ x[b]  (M=16 j, N=256 l, K=128 i) ----
    {
        f32x4 acc[4];
        #pragma unroll
        for (int f = 0; f < 4; ++f) acc[f] = (f32x4){0.f, 0.f, 0.f, 0.f};
        const unsigned short* Bb = xbT + (size_t)b * 32768;
        #pragma unroll
        for (int ks = 0; ks < 4; ++ks) {
            bf16x8 af = *(const bf16x8*)&adjL[lr * 144 + ks * 32 + lg * 8];
            #pragma unroll
            for (int f = 0; f < 4; ++f) {
                bf16x8 bv = *(const bf16x8*)(Bb + (size_t)(w * 64 + f * 16 + lr) * 128 + ks * 32 + lg * 8);
                acc[f] = __builtin_amdgcn_mfma_f32_16x16x32_bf16(af, bv, acc[f], 0, 0, 0);
            }
        }
        #pragma unroll
        for (int f = 0; f < 4; ++f)
            #pragma unroll
            for (int r = 0; r < 4; ++r)
                yL[(lg * 4 + r) * 272 + w * 64 + f * 16 + lr] = (short)f2bf(acc[f][r]);
    }
    __syncthreads();

    // ---- Phase B: out half (M=16 j, N=128, K=512) ----
    {
        f32x4 o[2];
        o[0] = (f32x4){0.f, 0.f, 0.f, 0.f};
        o[1] = (f32x4){0.f, 0.f, 0.f, 0.f};
        const unsigned short* Arow = xb + (size_t)b * 32768 + (size_t)(j0 + lr) * 256;
        #pragma unroll
        for (int ks = 0; ks < 16; ++ks) {
            bf16x8 af = (ks < 8)
                ? *(const bf16x8*)(Arow + ks * 32 + lg * 8)
                : *(const bf16x8*)&yL[lr * 272 + (ks - 8) * 32 + lg * 8];
            #pragma unroll
            for (int f = 0; f < 2; ++f) {
                int n = nh * 128 + w * 32 + f * 16 + lr;
                bf16x8 bv = *(const bf16x8*)(thT2 + (size_t)n * 512 + ks * 32 + lg * 8);
                o[f] = __builtin_amdgcn_mfma_f32_16x16x32_bf16(af, bv, o[f], 0, 0, 0);
            }
        }
        float* Ob = out + (size_t)b * 32768;
        #pragma unroll
        for (int f = 0; f < 2; ++f)
            #pragma unroll
            for (int r = 0; r < 4; ++r)
                Ob[(size_t)(j0 + lg * 4 + r) * 256 + nh * 128 + w * 32 + f * 16 + lr] =
                    fmaxf(o[f][r], 0.f);
    }
}

extern "C" void kernel_launch(void* const* d_in, const int* in_sizes, int n_in,
                              void* d_out, int out_size, void* d_ws, size_t ws_size,
                              hipStream_t stream) {
    const float* x     = (const float*)d_in[0];   // [32,128,256]
    const float* a     = (const float*)d_in[1];   // [128,128]
    const float* Theta = (const float*)d_in[2];   // [2,256,256]
    float* out = (float*)d_out;
    float* f0  = (float*)d_ws;

    float*          diff  = f0;                                // 524288 f32 (2 MB)
    float*          ssum  = f0 + 524288;                       // 16384 f32
    float*          aT    = f0 + 540672;                       // 16384 f32
    unsigned short* xb    = (unsigned short*)(f0 + 557056);    // 1048576 bf16
    unsigned short* xbT   = (unsigned short*)(f0 + 1081344);   // 1048576 bf16
    unsigned short* thT2  = (unsigned short*)(f0 + 1605632);   // 131072 bf16
    // total 1671168 f32 = 6.68 MB

    hipMemsetAsync(ssum, 0, 16384 * sizeof(float), stream);
    k_pre <<<dim3(612), dim3(256), 0, stream>>>(x, Theta, a, diff, ssum, xb, xbT, thT2, aT);
    k_fuse<<<dim3(512), dim3(256), 0, stream>>>(diff, ssum, aT, xb, xbT, thT2, out);
}